// Round 2
// baseline (173.840 us; speedup 1.0000x reference)
//
#include <hip/hip_runtime.h>

#define TDIM 128

__device__ __forceinline__ float u2f(unsigned int u) {
  union { unsigned int u; float f; } w; w.u = u; return w.f;
}
__device__ __forceinline__ float bf2f(unsigned short v) {
  return u2f(((unsigned int)v) << 16);
}
__device__ __forceinline__ unsigned short f2bf(float x) {
  union { float f; unsigned int u; } w; w.f = x;
  unsigned int u = w.u;
  u += 0x7fffu + ((u >> 16) & 1u);   // round-to-nearest-even
  return (unsigned short)(u >> 16);
}

// Persistent-block version. Grid = min(nrows, 1024) = exactly 4 blocks/CU;
// each block stages the WHOLE clms (64x128 f32 = 32 KB LDS) once, syncs once,
// then grid-strides over output rows with zero further barriers and zero
// further global reads except <=15 broadcast CG scalars per row.
// Rationale: mandatory work is ~79 MB stores (12.6 us) + ~8 us VALU, but the
// measured kernel is far above that -> per-block staging latency + barrier
// chains dominate, so amortize them 2.4x and let rows pipeline freely.
__global__ __launch_bounds__(256, 4)
void cg_kernel(const void* __restrict__ clms_raw,
               const void* __restrict__ C_raw,
               void* __restrict__ out_raw,
               const int nrows) {
  __shared__ float sc[64 * TDIM];   // full clms, upcast to f32 (32 KB)

  const int tid = threadIdx.x;

  // ---- dtype sniff (uniform; once per block, 1024 blocks total) ----
  const unsigned int* cw = (const unsigned int*)clms_raw;
  int nbf = 0;
  #pragma unroll
  for (int i = 0; i < 32; ++i) {
    unsigned int e = (cw[i] >> 7) & 0xFFu;
    nbf += (e >= 110u && e <= 135u) ? 1 : 0;
  }
  const bool in_bf16 = (nbf >= 16);
  const bool c_bf16 = ((*(const unsigned int*)C_raw) & 0xffffu) == 0x3f80u;

  // ---- stage full clms into LDS as f32 (ONCE per block) ----
  if (in_bf16) {
    const uint4* cl4 = (const uint4*)clms_raw;   // 8192 bf16 = 1024 uint4
    #pragma unroll
    for (int it = 0; it < 4; ++it) {
      int v = tid + it * 256;
      uint4 w = cl4[v];
      float4* dst = (float4*)&sc[v * 8];
      float4 d0, d1;
      d0.x = u2f(w.x << 16); d0.y = u2f(w.x & 0xffff0000u);
      d0.z = u2f(w.y << 16); d0.w = u2f(w.y & 0xffff0000u);
      d1.x = u2f(w.z << 16); d1.y = u2f(w.z & 0xffff0000u);
      d1.z = u2f(w.w << 16); d1.w = u2f(w.w & 0xffff0000u);
      dst[0] = d0; dst[1] = d1;
    }
  } else {
    const float4* cf4 = (const float4*)clms_raw; // 8192 f32 = 2048 float4
    float4* sc4 = (float4*)sc;
    #pragma unroll
    for (int it = 0; it < 8; ++it) {
      int v = tid + it * 256;
      sc4[v] = cf4[v];
    }
  }
  __syncthreads();   // the ONLY barrier in the kernel

  const int tx = tid & 31;
  const int ty = tid >> 5;
  const int t2 = tx * 4;

  for (int r = blockIdx.x; r < nrows; r += gridDim.x) {
    // ---- decode r -> (l, m, l1, l2); closed-form, uniform ----
    int l = 0, cum = 0, pc = 8;
    if (r >= 8)    { l = 1; cum = 8;    pc = 21; }
    if (r >= 71)   { l = 2; cum = 71;   pc = 31; }
    if (r >= 226)  { l = 3; cum = 226;  pc = 38; }
    if (r >= 492)  { l = 4; cum = 492;  pc = 42; }
    if (r >= 870)  { l = 5; cum = 870;  pc = 43; }
    if (r >= 1343) { l = 6; cum = 1343; pc = 41; }
    if (r >= 1876) { l = 7; cum = 1876; pc = 36; }
    const int rem = r - cum;
    const int mi  = rem / pc;
    const int m   = mi - l;
    int pp = rem - mi * pc;
    int l1 = 0, l2 = 0, found = 0;
    #pragma unroll
    for (int a = 0; a < 8; ++a) {    // pair -> (l1,l2): contiguous l2 ranges
      int d = a - l; if (d < 0) d = -d;
      int hi = a + l; if (hi > 7) hi = 7;
      int na = hi - d + 1;
      if (!found && pp < na) { l1 = a; l2 = d + pp; found = 1; }
      if (!found) pp -= na;
    }

    const int m1lo = (-l1 > m - l2) ? -l1 : (m - l2);
    const int m1hi = ( l1 < m + l2) ?  l1 : (m + l2);
    const int nnz = m1hi - m1lo + 1;           // 1..15, uniform
    const int i0 = l1 * (l1 + 1) + m1lo;       // A rows: i0+q
    const int j0 = l2 * (l2 + 1) + (m - m1lo); // B rows: j0-q
    const int k0 = l * (l + 1) + m;

    // ---- per-row B fragments, CG coefficient folded in (b[q]=0 for q>=nnz)
    float4 b[15];
    #pragma unroll
    for (int q = 0; q < 15; ++q) {
      const int qc = (q < nnz) ? q : 0;        // clamp keeps LDS addr in-range
      float cq = 0.0f;
      if (q < nnz) {                           // uniform; broadcast global load
        int ci = (k0 * 64 + i0 + q) * 64 + (j0 - q);
        cq = c_bf16 ? bf2f(((const unsigned short*)C_raw)[ci])
                    : ((const float*)C_raw)[ci];
      }
      const float4 v = *(const float4*)&sc[(j0 - qc) * TDIM + t2];
      b[q] = make_float4(cq * v.x, cq * v.y, cq * v.z, cq * v.w);
    }

    const unsigned long long outbase =
        (unsigned long long)r * (TDIM * TDIM) + (unsigned int)t2;

    if (in_bf16) {
      unsigned short* out = (unsigned short*)out_raw;
      #pragma unroll
      for (int s0 = 0; s0 < 4; ++s0) {
        const int t1b = ty + 32 * s0;
        float4 acc[4];
        #pragma unroll
        for (int d = 0; d < 4; ++d) acc[d] = make_float4(0.f, 0.f, 0.f, 0.f);
        #pragma unroll
        for (int q = 0; q < 15; ++q) {
          if (q < nnz) {                       // uniform -> scalar branch
            #pragma unroll
            for (int d = 0; d < 4; ++d) {
              float a = sc[(i0 + q) * TDIM + t1b + 8 * d];  // broadcast read
              acc[d].x += a * b[q].x;
              acc[d].y += a * b[q].y;
              acc[d].z += a * b[q].z;
              acc[d].w += a * b[q].w;
            }
          }
        }
        #pragma unroll
        for (int d = 0; d < 4; ++d) {
          ushort4 o;
          o.x = f2bf(acc[d].x); o.y = f2bf(acc[d].y);
          o.z = f2bf(acc[d].z); o.w = f2bf(acc[d].w);
          *(ushort4*)(out + outbase +
                      (unsigned long long)((t1b + 8 * d) * TDIM)) = o;
        }
      }
    } else {
      float* out = (float*)out_raw;
      #pragma unroll
      for (int s0 = 0; s0 < 4; ++s0) {
        const int t1b = ty + 32 * s0;
        float4 acc[4];
        #pragma unroll
        for (int d = 0; d < 4; ++d) acc[d] = make_float4(0.f, 0.f, 0.f, 0.f);
        #pragma unroll
        for (int q = 0; q < 15; ++q) {
          if (q < nnz) {
            #pragma unroll
            for (int d = 0; d < 4; ++d) {
              float a = sc[(i0 + q) * TDIM + t1b + 8 * d];
              acc[d].x += a * b[q].x;
              acc[d].y += a * b[q].y;
              acc[d].z += a * b[q].z;
              acc[d].w += a * b[q].w;
            }
          }
        }
        #pragma unroll
        for (int d = 0; d < 4; ++d)
          *(float4*)(out + outbase +
                     (unsigned long long)((t1b + 8 * d) * TDIM)) = acc[d];
      }
    }
  }
}

extern "C" void kernel_launch(void* const* d_in, const int* in_sizes, int n_in,
                              void* d_out, int out_size, void* d_ws, size_t ws_size,
                              hipStream_t stream) {
  (void)in_sizes; (void)n_in; (void)d_ws; (void)ws_size;
  const int nrows = out_size / (TDIM * TDIM);   // 2416 for L=7, T=128
  const int grid = (nrows < 1024) ? nrows : 1024;  // 4 blocks/CU, one generation
  cg_kernel<<<grid, 256, 0, stream>>>(d_in[0], d_in[1], d_out, nrows);
}